// Round 2
// baseline (463.614 us; speedup 1.0000x reference)
//
#include <hip/hip_runtime.h>

// Problem constants (B,C,N,H from reference; D=DV=C)
#define Bb 4
#define Cc 256
#define Nn 1024
#define Hh 8
#define Oo 2048  // H*D

typedef __attribute__((ext_vector_type(8))) short bf16x8;  // 8 bf16 = 4 VGPRs
typedef __attribute__((ext_vector_type(4))) float f32x4;

__device__ __forceinline__ short f2bf(float f) {
  unsigned u = __builtin_bit_cast(unsigned, f);
  unsigned r = u + 0x7FFFu + ((u >> 16) & 1u);  // RNE
  return (short)(r >> 16);
}
__device__ __forceinline__ f32x4 mfma16(bf16x8 a, bf16x8 b, f32x4 c) {
  return __builtin_amdgcn_mfma_f32_16x16x32_bf16(a, b, c, 0, 0, 0);
}

// ---------------------------------------------------------------------------
// K0a: pack fp32 weight matrix -> bf16 (row-major [O,C] preserved).
// grid: n/1024 blocks of 256, 4 elems/thread.
__global__ __launch_bounds__(256) void k_pack(const float* __restrict__ src,
                                              short* __restrict__ dst, int n) {
  int i = (blockIdx.x * 256 + threadIdx.x) * 4;
  if (i + 3 < n) {
    float4 v = *(const float4*)(src + i);
    short4 o;
    o.x = f2bf(v.x);
    o.y = f2bf(v.y);
    o.z = f2bf(v.z);
    o.w = f2bf(v.w);
    *(short4*)(dst + i) = o;
  }
}

// ---------------------------------------------------------------------------
// K0b: transpose+convert x,y [B,C,N] f32 -> xT,yT [B,N,C] bf16.
// grid: (N/64, C/64, 2*B), block 256
__global__ __launch_bounds__(256) void k_transpose(
    const float* __restrict__ x, const float* __restrict__ y,
    short* __restrict__ xT, short* __restrict__ yT) {
  int bz = blockIdx.z;
  int b = bz >> 1;
  const float* src = (bz & 1) ? y : x;
  short* dst = (bz & 1) ? yT : xT;
  src += (size_t)b * Cc * Nn;
  dst += (size_t)b * Nn * Cc;
  __shared__ short tile[64][72];
  int n0 = blockIdx.x * 64, c0 = blockIdx.y * 64;
  int t = threadIdx.x;
#pragma unroll
  for (int i = 0; i < 16; i++) {
    int idx = t + i * 256;
    int cc = idx >> 6, nn = idx & 63;
    tile[cc][nn] = f2bf(src[(size_t)(c0 + cc) * Nn + n0 + nn]);
  }
  __syncthreads();
#pragma unroll
  for (int i = 0; i < 16; i++) {
    int idx = t + i * 256;
    int nn = idx >> 6, cc = idx & 63;
    dst[(size_t)(n0 + nn) * Cc + c0 + cc] = tile[cc][nn];
  }
}

// ---------------------------------------------------------------------------
// K1: fused Q,K projection.  Qt/Kt[b][h][n][d] = bq[o] + sum_c x[b][c][n]*W[o][c]
// out tile: rows=n (64), cols=o (64); A frags from xT shared between Q and K.
// grid: (N/64, O/64, B), block 256 (wave w owns rows w*16..w*16+15)
__global__ __launch_bounds__(256) void k_proj_qk(
    const short* __restrict__ xT, const short* __restrict__ Wq,
    const float* __restrict__ bq, const short* __restrict__ Wk,
    const float* __restrict__ bk, short* __restrict__ Qt,
    short* __restrict__ Kt) {
  int b = blockIdx.z, n0 = blockIdx.x * 64, o0 = blockIdx.y * 64;
  int wave = threadIdx.x >> 6, lane = threadIdx.x & 63;
  int quad = lane >> 4, l16 = lane & 15;
  const short* aptr =
      xT + (size_t)b * Nn * Cc + (size_t)(n0 + wave * 16 + l16) * Cc + quad * 8;
  f32x4 accQ[4], accK[4];
#pragma unroll
  for (int j = 0; j < 4; j++) {
    accQ[j] = f32x4{0.f, 0.f, 0.f, 0.f};
    accK[j] = f32x4{0.f, 0.f, 0.f, 0.f};
  }
#pragma unroll
  for (int ks = 0; ks < 8; ks++) {
    bf16x8 a = *(const bf16x8*)(aptr + ks * 32);
#pragma unroll
    for (int cj = 0; cj < 4; cj++) {
      int o = o0 + cj * 16 + l16;
      bf16x8 wqf = *(const bf16x8*)(Wq + (size_t)o * Cc + ks * 32 + quad * 8);
      bf16x8 wkf = *(const bf16x8*)(Wk + (size_t)o * Cc + ks * 32 + quad * 8);
      accQ[cj] = mfma16(a, wqf, accQ[cj]);
      accK[cj] = mfma16(a, wkf, accK[cj]);
    }
  }
  // C-frag: row n = n0+wave*16+quad*4+r, col o = o0+cj*16+l16
#pragma unroll
  for (int cj = 0; cj < 4; cj++) {
    int o = o0 + cj * 16 + l16;
    int h = o >> 8, d = o & 255;
    float vbq = bq[o];
    float vbk = bk[o];
#pragma unroll
    for (int r = 0; r < 4; r++) {
      int n = n0 + wave * 16 + quad * 4 + r;
      size_t idx = (((size_t)(b * Hh + h) * Nn) + n) * 256 + d;
      Qt[idx] = f2bf(accQ[cj][r] + vbq);
      Kt[idx] = f2bf(accK[cj][r] + vbk);
    }
  }
}

// ---------------------------------------------------------------------------
// K2: V / yp projection. out[b][o][n] = bias[o] + sum_c W[o][c]*y[b][c][n]
// rows=o (64), cols=n (64); A from packed W (c-contig), B from yT (c-contig).
// grid: (N/64, Ot/64, B), block 256
template <bool FP32OUT>
__global__ __launch_bounds__(256) void k_proj_on(
    const short* __restrict__ yTs, const short* __restrict__ W,
    const float* __restrict__ bias, void* __restrict__ outp, int Ot) {
  int b = blockIdx.z, n0 = blockIdx.x * 64, o0 = blockIdx.y * 64;
  int wave = threadIdx.x >> 6, lane = threadIdx.x & 63;
  int quad = lane >> 4, l16 = lane & 15;
  const short* aptr = W + (size_t)(o0 + wave * 16 + l16) * Cc + quad * 8;
  const short* bbase = yTs + (size_t)b * Nn * Cc + quad * 8;
  f32x4 acc[4];
#pragma unroll
  for (int j = 0; j < 4; j++) acc[j] = f32x4{0.f, 0.f, 0.f, 0.f};
#pragma unroll
  for (int ks = 0; ks < 8; ks++) {
    bf16x8 a = *(const bf16x8*)(aptr + ks * 32);
#pragma unroll
    for (int cj = 0; cj < 4; cj++) {
      int n = n0 + cj * 16 + l16;
      bf16x8 bb = *(const bf16x8*)(bbase + (size_t)n * Cc + ks * 32);
      acc[cj] = mfma16(a, bb, acc[cj]);
    }
  }
#pragma unroll
  for (int cj = 0; cj < 4; cj++) {
    int n = n0 + cj * 16 + l16;
#pragma unroll
    for (int r = 0; r < 4; r++) {
      int o = o0 + wave * 16 + quad * 4 + r;
      float v = acc[cj][r] + (bias ? bias[o] : 0.f);
      size_t idx = ((size_t)b * Ot + o) * Nn + n;
      if (FP32OUT)
        ((float*)outp)[idx] = v;
      else
        ((short*)outp)[idx] = f2bf(v);
    }
  }
}

// ---------------------------------------------------------------------------
// K3: flash attention + fused epilogue (gamma blend with yp, fp32 out).
// grid: (N/64 query tiles, H, B), block 256. Wave w owns query rows w*16..+15.
// Q tile in registers; K/V frags direct from global (L2); P via LDS C->A
// layout round-trip; O written straight from C-frag as float4 along q.
__global__ __launch_bounds__(256) void k_attn(
    const short* __restrict__ Qt, const short* __restrict__ Kt,
    const short* __restrict__ Vv, const float* __restrict__ yp,
    const float* __restrict__ gamma, float* __restrict__ out) {
  int b = blockIdx.z, h = blockIdx.y, q0 = blockIdx.x * 64;
  int wave = threadIdx.x >> 6, lane = threadIdx.x & 63;
  int quad = lane >> 4, l16 = lane & 15;
  size_t bh = (size_t)(b * Hh + h);
  const short* Qb = Qt + bh * Nn * 256;
  const short* Kb = Kt + bh * Nn * 256;
  const short* Vb = Vv + bh * (size_t)256 * Nn;  // [dv][n]

  // Q rows for this wave, in registers: A[m=l16][k=ks*32+quad*8+j]
  bf16x8 qreg[8];
  {
    const short* qp = Qb + (size_t)(q0 + wave * 16 + l16) * 256 + quad * 8;
#pragma unroll
    for (int ks = 0; ks < 8; ks++) qreg[ks] = *(const bf16x8*)(qp + ks * 32);
  }
  f32x4 oacc[16];
#pragma unroll
  for (int j = 0; j < 16; j++) oacc[j] = f32x4{0.f, 0.f, 0.f, 0.f};
  float m_i[4], l_i[4];
#pragma unroll
  for (int r = 0; r < 4; r++) {
    m_i[r] = -1e30f;
    l_i[r] = 0.f;
  }

  __shared__ __align__(16) short plds[4][16][72];  // per-wave P tile [q][key]

  for (int kt = 0; kt < 16; kt++) {
    int k0 = kt * 64;
    // S tile [16 q][64 keys] per wave
    f32x4 sc[4];
#pragma unroll
    for (int j = 0; j < 4; j++) sc[j] = f32x4{0.f, 0.f, 0.f, 0.f};
#pragma unroll
    for (int ks = 0; ks < 8; ks++) {
#pragma unroll
      for (int cj = 0; cj < 4; cj++) {
        bf16x8 kb = *(const bf16x8*)(Kb + (size_t)(k0 + cj * 16 + l16) * 256 +
                                     ks * 32 + quad * 8);
        sc[cj] = mfma16(qreg[ks], kb, sc[cj]);
      }
    }
    // online softmax: S rows live in quads (row = quad*4+r), cols = cj*16+l16
    float alpha[4];
#pragma unroll
    for (int r = 0; r < 4; r++) {
      float v = fmaxf(fmaxf(sc[0][r], sc[1][r]), fmaxf(sc[2][r], sc[3][r]));
      v = fmaxf(v, __shfl_xor(v, 1));
      v = fmaxf(v, __shfl_xor(v, 2));
      v = fmaxf(v, __shfl_xor(v, 4));
      v = fmaxf(v, __shfl_xor(v, 8));
      float mn = fmaxf(m_i[r], v);
      alpha[r] = __expf(m_i[r] - mn);
      m_i[r] = mn;
    }
    float rs[4] = {0.f, 0.f, 0.f, 0.f};
#pragma unroll
    for (int cj = 0; cj < 4; cj++) {
#pragma unroll
      for (int r = 0; r < 4; r++) {
        float p = __expf(sc[cj][r] - m_i[r]);
        rs[r] += p;
        plds[wave][quad * 4 + r][cj * 16 + l16] = f2bf(p);
      }
    }
#pragma unroll
    for (int r = 0; r < 4; r++) {
      float v = rs[r];
      v += __shfl_xor(v, 1);
      v += __shfl_xor(v, 2);
      v += __shfl_xor(v, 4);
      v += __shfl_xor(v, 8);
      l_i[r] = l_i[r] * alpha[r] + v;
    }
#pragma unroll
    for (int j = 0; j < 16; j++)
#pragma unroll
      for (int r = 0; r < 4; r++) oacc[j][r] *= alpha[r];
    __syncthreads();  // order LDS P-writes before cross-lane reads
    // P in A-layout: A[m=l16][k=quad*8+j (+32)]
    bf16x8 ap0 = *(const bf16x8*)&plds[wave][l16][quad * 8];
    bf16x8 ap1 = *(const bf16x8*)&plds[wave][l16][32 + quad * 8];
#pragma unroll
    for (int dj = 0; dj < 16; dj++) {
      const short* vp = Vb + (size_t)(dj * 16 + l16) * Nn + k0 + quad * 8;
      bf16x8 v0 = *(const bf16x8*)vp;
      bf16x8 v1 = *(const bf16x8*)(vp + 32);
      oacc[dj] = mfma16(ap0, v0, oacc[dj]);
      oacc[dj] = mfma16(ap1, v1, oacc[dj]);
    }
  }
  // epilogue: O[q][dv] in C-frag (row q=quad*4+r, col dv=dj*16+l16);
  // out[b][h*256+dv][q] — float4 over r is contiguous in q.
  float gf = gamma[h];
  float sg = gf / (1.f + gf), sy = 1.f / (1.f + gf);
  int qq = q0 + wave * 16 + quad * 4;
#pragma unroll
  for (int dj = 0; dj < 16; dj++) {
    int dv = dj * 16 + l16;
    const float* ypp = yp + ((size_t)b * 256 + dv) * Nn + qq;
    float* op = out + ((size_t)b * Oo + h * 256 + dv) * Nn + qq;
    float4 yv = *(const float4*)ypp;
    float4 ov;
    ov.x = sg * (oacc[dj][0] / l_i[0]) + sy * yv.x;
    ov.y = sg * (oacc[dj][1] / l_i[1]) + sy * yv.y;
    ov.z = sg * (oacc[dj][2] / l_i[2]) + sy * yv.z;
    ov.w = sg * (oacc[dj][3] / l_i[3]) + sy * yv.w;
    *(float4*)op = ov;
  }
}

// ---------------------------------------------------------------------------
extern "C" void kernel_launch(void* const* d_in, const int* in_sizes, int n_in,
                              void* d_out, int out_size, void* d_ws,
                              size_t ws_size, hipStream_t stream) {
  const float* x = (const float*)d_in[0];
  const float* y = (const float*)d_in[1];
  const float* Wq = (const float*)d_in[2];
  const float* bq = (const float*)d_in[3];
  const float* Wk = (const float*)d_in[4];
  const float* bk = (const float*)d_in[5];
  const float* Wv = (const float*)d_in[6];
  const float* bv = (const float*)d_in[7];
  const float* Wp = (const float*)d_in[8];
  const float* gamma = (const float*)d_in[9];
  float* out = (float*)d_out;

  char* w = (char*)d_ws;
  short* Qt = (short*)(w + 0);          // 16 MB  [B,H,N,256] bf16
  short* Kt = (short*)(w + 16777216);   // 16 MB  [B,H,N,256] bf16
  short* Vv = (short*)(w + 33554432);   // 16 MB  [B,H*256,N] bf16
  short* xT = (short*)(w + 50331648);   // 2 MB   [B,N,C] bf16
  short* yT = (short*)(w + 52428800);   // 2 MB   [B,N,C] bf16
  float* yp = (float*)(w + 54525952);   // 4 MB   [B,256,N] f32
  short* Wqb = (short*)(w + 58720256);  // 1 MB   [2048,256] bf16
  short* Wkb = (short*)(w + 59768832);  // 1 MB
  short* Wvb = (short*)(w + 60817408);  // 1 MB
  short* Wpb = (short*)(w + 61865984);  // 128 KB [256,256] bf16

  k_pack<<<dim3(512), dim3(256), 0, stream>>>(Wq, Wqb, Oo * Cc);
  k_pack<<<dim3(512), dim3(256), 0, stream>>>(Wk, Wkb, Oo * Cc);
  k_pack<<<dim3(512), dim3(256), 0, stream>>>(Wv, Wvb, Oo * Cc);
  k_pack<<<dim3(64), dim3(256), 0, stream>>>(Wp, Wpb, Cc * Cc);
  k_transpose<<<dim3(Nn / 64, Cc / 64, 2 * Bb), dim3(256), 0, stream>>>(
      x, y, xT, yT);
  k_proj_qk<<<dim3(Nn / 64, Oo / 64, Bb), dim3(256), 0, stream>>>(
      xT, Wqb, bq, Wkb, bk, Qt, Kt);
  k_proj_on<false><<<dim3(Nn / 64, Oo / 64, Bb), dim3(256), 0, stream>>>(
      yT, Wvb, bv, (void*)Vv, Oo);
  k_proj_on<true><<<dim3(Nn / 64, Cc / 64, Bb), dim3(256), 0, stream>>>(
      yT, Wpb, nullptr, (void*)yp, Cc);
  k_attn<<<dim3(Nn / 64, Hh, Bb), dim3(256), 0, stream>>>(
      Qt, Kt, Vv, yp, gamma, out);
}

// Round 3
// 274.827 us; speedup vs baseline: 1.6869x; 1.6869x over previous
//
#include <hip/hip_runtime.h>

// Problem constants (B,C,N,H from reference; D=DV=C)
#define Bb 4
#define Cc 256
#define Nn 1024
#define Hh 8
#define Oo 2048  // H*D

typedef __attribute__((ext_vector_type(8))) short bf16x8;  // 8 bf16 = 4 VGPRs
typedef __attribute__((ext_vector_type(4))) float f32x4;

__device__ __forceinline__ short f2bf(float f) {
  unsigned u = __builtin_bit_cast(unsigned, f);
  unsigned r = u + 0x7FFFu + ((u >> 16) & 1u);  // RNE
  return (short)(r >> 16);
}
__device__ __forceinline__ f32x4 mfma16(bf16x8 a, bf16x8 b, f32x4 c) {
  return __builtin_amdgcn_mfma_f32_16x16x32_bf16(a, b, c, 0, 0, 0);
}
// async global->LDS, 16B per lane; LDS dst = (uniform base) + lane*16
__device__ __forceinline__ void gl_lds16(const void* g, void* l) {
  __builtin_amdgcn_global_load_lds(
      (const __attribute__((address_space(1))) void*)g,
      (__attribute__((address_space(3))) void*)l, 16, 0, 0);
}

// ---------------------------------------------------------------------------
// K0a: pack fp32 weight matrix -> bf16 (row-major [O,C] preserved).
__global__ __launch_bounds__(256) void k_pack(const float* __restrict__ src,
                                              short* __restrict__ dst, int n) {
  int i = (blockIdx.x * 256 + threadIdx.x) * 4;
  if (i + 3 < n) {
    float4 v = *(const float4*)(src + i);
    short4 o;
    o.x = f2bf(v.x);
    o.y = f2bf(v.y);
    o.z = f2bf(v.z);
    o.w = f2bf(v.w);
    *(short4*)(dst + i) = o;
  }
}

// ---------------------------------------------------------------------------
// K0b: transpose+convert x,y [B,C,N] f32 -> xT,yT [B,N,C] bf16.
__global__ __launch_bounds__(256) void k_transpose(
    const float* __restrict__ x, const float* __restrict__ y,
    short* __restrict__ xT, short* __restrict__ yT) {
  int bz = blockIdx.z;
  int b = bz >> 1;
  const float* src = (bz & 1) ? y : x;
  short* dst = (bz & 1) ? yT : xT;
  src += (size_t)b * Cc * Nn;
  dst += (size_t)b * Nn * Cc;
  __shared__ short tile[64][72];
  int n0 = blockIdx.x * 64, c0 = blockIdx.y * 64;
  int t = threadIdx.x;
#pragma unroll
  for (int i = 0; i < 16; i++) {
    int idx = t + i * 256;
    int cc = idx >> 6, nn = idx & 63;
    tile[cc][nn] = f2bf(src[(size_t)(c0 + cc) * Nn + n0 + nn]);
  }
  __syncthreads();
#pragma unroll
  for (int i = 0; i < 16; i++) {
    int idx = t + i * 256;
    int nn = idx >> 6, cc = idx & 63;
    dst[(size_t)(n0 + nn) * Cc + c0 + cc] = tile[cc][nn];
  }
}

// ---------------------------------------------------------------------------
// K1: fused Q,K projection. Wq/Wk tiles staged in LDS (shared by all 4 waves);
// per-wave x A-frags prefetched to registers. grid (N/64, O/64, B), block 256.
__global__ __launch_bounds__(256) void k_proj_qk(
    const short* __restrict__ xT, const short* __restrict__ Wq,
    const float* __restrict__ bq, const short* __restrict__ Wk,
    const float* __restrict__ bk, short* __restrict__ Qt,
    short* __restrict__ Kt) {
  int b = blockIdx.z, n0 = blockIdx.x * 64, o0 = blockIdx.y * 64;
  int wave = threadIdx.x >> 6, lane = threadIdx.x & 63;
  int quad = lane >> 4, l16 = lane & 15;
  __shared__ short Wqs[64 * 256];  // 32 KB, [o][c]
  __shared__ short Wks[64 * 256];  // 32 KB

  const char* wqg = (const char*)(Wq + (size_t)o0 * Cc);
  const char* wkg = (const char*)(Wk + (size_t)o0 * Cc);
#pragma unroll
  for (int i = 0; i < 8; i++) {
    int off = (wave * 8 + i) * 1024;
    gl_lds16(wqg + off + lane * 16, (char*)Wqs + off);
    gl_lds16(wkg + off + lane * 16, (char*)Wks + off);
  }
  // A frags to registers (vmcnt drained by the barrier below)
  const short* aptr =
      xT + (size_t)b * Nn * Cc + (size_t)(n0 + wave * 16 + l16) * Cc + quad * 8;
  bf16x8 areg[8];
#pragma unroll
  for (int ks = 0; ks < 8; ks++) areg[ks] = *(const bf16x8*)(aptr + ks * 32);

  f32x4 accQ[4], accK[4];
#pragma unroll
  for (int j = 0; j < 4; j++) {
    accQ[j] = f32x4{0.f, 0.f, 0.f, 0.f};
    accK[j] = f32x4{0.f, 0.f, 0.f, 0.f};
  }
  __syncthreads();
#pragma unroll
  for (int ks = 0; ks < 8; ks++) {
#pragma unroll
    for (int cj = 0; cj < 4; cj++) {
      int row = (cj * 16 + l16) * 256 + ks * 32 + quad * 8;
      bf16x8 wqf = *(const bf16x8*)&Wqs[row];
      bf16x8 wkf = *(const bf16x8*)&Wks[row];
      accQ[cj] = mfma16(areg[ks], wqf, accQ[cj]);
      accK[cj] = mfma16(areg[ks], wkf, accK[cj]);
    }
  }
  // C-frag: row n = n0+wave*16+quad*4+r, col o = o0+cj*16+l16
#pragma unroll
  for (int cj = 0; cj < 4; cj++) {
    int o = o0 + cj * 16 + l16;
    int h = o >> 8, d = o & 255;
    float vbq = bq[o];
    float vbk = bk[o];
#pragma unroll
    for (int r = 0; r < 4; r++) {
      int n = n0 + wave * 16 + quad * 4 + r;
      size_t idx = (((size_t)(b * Hh + h) * Nn) + n) * 256 + d;
      Qt[idx] = f2bf(accQ[cj][r] + vbq);
      Kt[idx] = f2bf(accK[cj][r] + vbk);
    }
  }
}

// ---------------------------------------------------------------------------
// K2: V / yp projection. yT tile (the wave-redundant B operand) staged in LDS;
// per-wave W A-frags in registers. grid (N/64, Ot/64, B), block 256.
template <bool FP32OUT>
__global__ __launch_bounds__(256) void k_proj_on(
    const short* __restrict__ yTs, const short* __restrict__ W,
    const float* __restrict__ bias, void* __restrict__ outp, int Ot) {
  int b = blockIdx.z, n0 = blockIdx.x * 64, o0 = blockIdx.y * 64;
  int wave = threadIdx.x >> 6, lane = threadIdx.x & 63;
  int quad = lane >> 4, l16 = lane & 15;
  __shared__ short Ys[64 * 256];  // 32 KB, [n][c]

  const char* yg = (const char*)(yTs + (size_t)b * Nn * Cc + (size_t)n0 * Cc);
#pragma unroll
  for (int i = 0; i < 8; i++) {
    int off = (wave * 8 + i) * 1024;
    gl_lds16(yg + off + lane * 16, (char*)Ys + off);
  }
  const short* aptr = W + (size_t)(o0 + wave * 16 + l16) * Cc + quad * 8;
  bf16x8 areg[8];
#pragma unroll
  for (int ks = 0; ks < 8; ks++) areg[ks] = *(const bf16x8*)(aptr + ks * 32);

  f32x4 acc[4];
#pragma unroll
  for (int j = 0; j < 4; j++) acc[j] = f32x4{0.f, 0.f, 0.f, 0.f};
  __syncthreads();
#pragma unroll
  for (int ks = 0; ks < 8; ks++) {
#pragma unroll
    for (int cj = 0; cj < 4; cj++) {
      bf16x8 bb = *(const bf16x8*)&Ys[(cj * 16 + l16) * 256 + ks * 32 + quad * 8];
      acc[cj] = mfma16(areg[ks], bb, acc[cj]);
    }
  }
#pragma unroll
  for (int cj = 0; cj < 4; cj++) {
    int n = n0 + cj * 16 + l16;
#pragma unroll
    for (int r = 0; r < 4; r++) {
      int o = o0 + wave * 16 + quad * 4 + r;
      float v = acc[cj][r] + (bias ? bias[o] : 0.f);
      size_t idx = ((size_t)b * Ot + o) * Nn + n;
      if (FP32OUT)
        ((float*)outp)[idx] = v;
      else
        ((short*)outp)[idx] = f2bf(v);
    }
  }
}

// ---------------------------------------------------------------------------
// K3: flash attention, K/V tiles staged in LDS via global_load_lds.
// grid: (N/64, H, B), block 256 (4 waves; wave w owns query rows w*16..+15).
// Loop: [barrier: tiles ready] S-mfma -> softmax -> [barrier] stage K(kt+1)
// (overlaps PV) -> PV-mfma -> [barrier] stage V(kt+1).
__global__ __launch_bounds__(256) void k_attn(
    const short* __restrict__ Qt, const short* __restrict__ Kt,
    const short* __restrict__ Vv, const float* __restrict__ yp,
    const float* __restrict__ gamma, float* __restrict__ out) {
  int b = blockIdx.z, h = blockIdx.y, q0 = blockIdx.x * 64;
  int wave = threadIdx.x >> 6, lane = threadIdx.x & 63;
  int quad = lane >> 4, l16 = lane & 15;
  size_t bh = (size_t)(b * Hh + h);
  const short* Qb = Qt + bh * Nn * 256;
  const char* Kg = (const char*)(Kt + bh * Nn * 256);   // rows: key, 512 B
  const char* Vg = (const char*)(Vv + bh * (size_t)256 * Nn);  // rows: dv, 2048 B

  __shared__ short Klds[64 * 256];       // 32 KB  [key][d]
  __shared__ short Vlds[256 * 64];       // 32 KB  [dv][n-in-tile]
  __shared__ short plds[4][16][64];      // 8 KB   per-wave P tile [q][key]

  // Q rows for this wave, in registers: A[m=l16][k=ks*32+quad*8+j]
  bf16x8 qreg[8];
  {
    const short* qp = Qb + (size_t)(q0 + wave * 16 + l16) * 256 + quad * 8;
#pragma unroll
    for (int ks = 0; ks < 8; ks++) qreg[ks] = *(const bf16x8*)(qp + ks * 32);
  }
  f32x4 oacc[16];
#pragma unroll
  for (int j = 0; j < 16; j++) oacc[j] = f32x4{0.f, 0.f, 0.f, 0.f};
  float m_i[4], l_i[4];
#pragma unroll
  for (int r = 0; r < 4; r++) {
    m_i[r] = -1e30f;
    l_i[r] = 0.f;
  }

  // prologue: stage tile 0 (K contiguous; V is a per-lane gather)
#pragma unroll
  for (int i = 0; i < 8; i++) {
    int off = (wave * 8 + i) * 1024;
    gl_lds16(Kg + off + lane * 16, (char*)Klds + off);
    int beta = off + lane * 16;
    gl_lds16(Vg + (beta >> 7) * 2048 + (beta & 127), (char*)Vlds + beta - lane * 16);
  }

  for (int kt = 0; kt < 16; kt++) {
    int k0 = kt * 64;
    __syncthreads();  // staged tiles ready (drains vmcnt) + wave sync
    // ---- S = Q K^T for this tile: [16 q][64 keys] per wave
    f32x4 sc[4];
#pragma unroll
    for (int j = 0; j < 4; j++) sc[j] = f32x4{0.f, 0.f, 0.f, 0.f};
#pragma unroll
    for (int ks = 0; ks < 8; ks++) {
#pragma unroll
      for (int cj = 0; cj < 4; cj++) {
        bf16x8 kb =
            *(const bf16x8*)&Klds[(cj * 16 + l16) * 256 + ks * 32 + quad * 8];
        sc[cj] = mfma16(qreg[ks], kb, sc[cj]);
      }
    }
    // ---- online softmax: rows = quad*4+r, cols = cj*16+l16
    float alpha[4];
#pragma unroll
    for (int r = 0; r < 4; r++) {
      float v = fmaxf(fmaxf(sc[0][r], sc[1][r]), fmaxf(sc[2][r], sc[3][r]));
      v = fmaxf(v, __shfl_xor(v, 1));
      v = fmaxf(v, __shfl_xor(v, 2));
      v = fmaxf(v, __shfl_xor(v, 4));
      v = fmaxf(v, __shfl_xor(v, 8));
      float mn = fmaxf(m_i[r], v);
      alpha[r] = __expf(m_i[r] - mn);
      m_i[r] = mn;
    }
    float rs[4] = {0.f, 0.f, 0.f, 0.f};
#pragma unroll
    for (int cj = 0; cj < 4; cj++) {
#pragma unroll
      for (int r = 0; r < 4; r++) {
        float p = __expf(sc[cj][r] - m_i[r]);
        rs[r] += p;
        plds[wave][quad * 4 + r][cj * 16 + l16] = f2bf(p);
      }
    }
#pragma unroll
    for (int r = 0; r < 4; r++) {
      float v = rs[r];
      v += __shfl_xor(v, 1);
      v += __shfl_xor(v, 2);
      v += __shfl_xor(v, 4);
      v += __shfl_xor(v, 8);
      l_i[r] = l_i[r] * alpha[r] + v;
    }
#pragma unroll
    for (int j = 0; j < 16; j++)
#pragma unroll
      for (int r = 0; r < 4; r++) oacc[j][r] *= alpha[r];
    __syncthreads();  // plds ready; all waves done reading Klds
    // stage K(kt+1) — overlaps PV compute below
    if (kt < 15) {
      const char* kg = Kg + (size_t)(k0 + 64) * 512;
#pragma unroll
      for (int i = 0; i < 8; i++) {
        int off = (wave * 8 + i) * 1024;
        gl_lds16(kg + off + lane * 16, (char*)Klds + off);
      }
    }
    // ---- PV: O += P V^T-frags from Vlds
    bf16x8 ap0 = *(const bf16x8*)&plds[wave][l16][quad * 8];
    bf16x8 ap1 = *(const bf16x8*)&plds[wave][l16][32 + quad * 8];
#pragma unroll
    for (int dj = 0; dj < 16; dj++) {
      const short* vp = &Vlds[(dj * 16 + l16) * 64 + quad * 8];
      bf16x8 v0 = *(const bf16x8*)vp;
      bf16x8 v1 = *(const bf16x8*)(vp + 32);
      oacc[dj] = mfma16(ap0, v0, oacc[dj]);
      oacc[dj] = mfma16(ap1, v1, oacc[dj]);
    }
    __syncthreads();  // all waves done reading Vlds (and plds)
    if (kt < 15) {
#pragma unroll
      for (int i = 0; i < 8; i++) {
        int beta = (wave * 8 + i) * 1024 + lane * 16;
        gl_lds16(Vg + (beta >> 7) * 2048 + (k0 + 64) * 2 + (beta & 127),
                 (char*)Vlds + beta - lane * 16);
      }
    }
  }
  // epilogue: O rows q=quad*4+r contiguous -> float4 stores; fuse gamma/yp
  float gf = gamma[h];
  float sg = gf / (1.f + gf), sy = 1.f / (1.f + gf);
  int qq = q0 + wave * 16 + quad * 4;
#pragma unroll
  for (int dj = 0; dj < 16; dj++) {
    int dv = dj * 16 + l16;
    const float* ypp = yp + ((size_t)b * 256 + dv) * Nn + qq;
    float* op = out + ((size_t)b * Oo + h * 256 + dv) * Nn + qq;
    float4 yv = *(const float4*)ypp;
    float4 ov;
    ov.x = sg * (oacc[dj][0] / l_i[0]) + sy * yv.x;
    ov.y = sg * (oacc[dj][1] / l_i[1]) + sy * yv.y;
    ov.z = sg * (oacc[dj][2] / l_i[2]) + sy * yv.z;
    ov.w = sg * (oacc[dj][3] / l_i[3]) + sy * yv.w;
    *(float4*)op = ov;
  }
}

// ---------------------------------------------------------------------------
extern "C" void kernel_launch(void* const* d_in, const int* in_sizes, int n_in,
                              void* d_out, int out_size, void* d_ws,
                              size_t ws_size, hipStream_t stream) {
  const float* x = (const float*)d_in[0];
  const float* y = (const float*)d_in[1];
  const float* Wq = (const float*)d_in[2];
  const float* bq = (const float*)d_in[3];
  const float* Wk = (const float*)d_in[4];
  const float* bk = (const float*)d_in[5];
  const float* Wv = (const float*)d_in[6];
  const float* bv = (const float*)d_in[7];
  const float* Wp = (const float*)d_in[8];
  const float* gamma = (const float*)d_in[9];
  float* out = (float*)d_out;

  char* w = (char*)d_ws;
  short* Qt = (short*)(w + 0);          // 16 MB  [B,H,N,256] bf16
  short* Kt = (short*)(w + 16777216);   // 16 MB  [B,H,N,256] bf16
  short* Vv = (short*)(w + 33554432);   // 16 MB  [B,H*256,N] bf16
  short* xT = (short*)(w + 50331648);   // 2 MB   [B,N,C] bf16
  short* yT = (short*)(w + 52428800);   // 2 MB   [B,N,C] bf16
  float* yp = (float*)(w + 54525952);   // 4 MB   [B,256,N] f32
  short* Wqb = (short*)(w + 58720256);  // 1 MB   [2048,256] bf16
  short* Wkb = (short*)(w + 59768832);  // 1 MB
  short* Wvb = (short*)(w + 60817408);  // 1 MB
  short* Wpb = (short*)(w + 61865984);  // 128 KB [256,256] bf16

  k_pack<<<dim3(512), dim3(256), 0, stream>>>(Wq, Wqb, Oo * Cc);
  k_pack<<<dim3(512), dim3(256), 0, stream>>>(Wk, Wkb, Oo * Cc);
  k_pack<<<dim3(512), dim3(256), 0, stream>>>(Wv, Wvb, Oo * Cc);
  k_pack<<<dim3(64), dim3(256), 0, stream>>>(Wp, Wpb, Cc * Cc);
  k_transpose<<<dim3(Nn / 64, Cc / 64, 2 * Bb), dim3(256), 0, stream>>>(
      x, y, xT, yT);
  k_proj_qk<<<dim3(Nn / 64, Oo / 64, Bb), dim3(256), 0, stream>>>(
      xT, Wqb, bq, Wkb, bk, Qt, Kt);
  k_proj_on<false><<<dim3(Nn / 64, Oo / 64, Bb), dim3(256), 0, stream>>>(
      yT, Wvb, bv, (void*)Vv, Oo);
  k_proj_on<true><<<dim3(Nn / 64, Cc / 64, Bb), dim3(256), 0, stream>>>(
      yT, Wpb, nullptr, (void*)yp, Cc);
  k_attn<<<dim3(Nn / 64, Hh, Bb), dim3(256), 0, stream>>>(
      Qt, Kt, Vv, yp, gamma, out);
}

// Round 5
// 207.245 us; speedup vs baseline: 2.2370x; 1.3261x over previous
//
#include <hip/hip_runtime.h>

// Problem constants (B,C,N,H from reference; D=DV=C)
#define Bb 4
#define Cc 256
#define Nn 1024
#define Hh 8
#define Oo 2048  // H*D

typedef __attribute__((ext_vector_type(8))) short bf16x8;  // 8 bf16 = 4 VGPRs
typedef __attribute__((ext_vector_type(4))) float f32x4;

__device__ __forceinline__ short f2bf(float f) {
  unsigned u = __builtin_bit_cast(unsigned, f);
  unsigned r = u + 0x7FFFu + ((u >> 16) & 1u);  // RNE
  return (short)(r >> 16);
}
__device__ __forceinline__ f32x4 mfma16(bf16x8 a, bf16x8 b, f32x4 c) {
  return __builtin_amdgcn_mfma_f32_16x16x32_bf16(a, b, c, 0, 0, 0);
}
// async global->LDS, 16B/lane; LDS dst = (wave-uniform base) + lane*16
__device__ __forceinline__ void gl_lds16(const void* g, void* l) {
  __builtin_amdgcn_global_load_lds(
      (const __attribute__((address_space(1))) void*)g,
      (__attribute__((address_space(3))) void*)l, 16, 0, 0);
}

// Stage a 64-row x 512-B tile (rows contiguous at gbase) into LDS with
// XOR-16B-chunk swizzle: physical chunk p of row r holds logical chunk
// p^(r&7). Readers at logical (row, chunk c) use physical c^(row&7).
// Spreads same-column fragment reads across all 8 bank groups (2-way = free).
__device__ __forceinline__ void stage_row512(const char* gbase, char* lds,
                                             int wave, int lane) {
#pragma unroll
  for (int i = 0; i < 8; i++) {
    int off = (wave * 8 + i) * 1024;
    int L = off + lane * 16;
    int r = L >> 9;
    int c = ((L >> 4) & 31) ^ (r & 7);
    gl_lds16(gbase + r * 512 + c * 16, lds + off);
  }
}
// Same for V: 256 rows x 128 B within a [dv][Nn] slab; row stride 2048 B,
// tile column offset k0*2 bytes.
__device__ __forceinline__ void stage_v(const char* Vg, char* lds, int k0,
                                        int wave, int lane) {
#pragma unroll
  for (int i = 0; i < 8; i++) {
    int off = (wave * 8 + i) * 1024;
    int L = off + lane * 16;
    int r = L >> 7;
    int c = ((L >> 4) & 7) ^ (r & 7);
    gl_lds16(Vg + (size_t)r * 2048 + k0 * 2 + c * 16, lds + off);
  }
}

// ---------------------------------------------------------------------------
// K0a: pack fp32 weight matrix -> bf16 (row-major [O,C] preserved).
__global__ __launch_bounds__(256) void k_pack(const float* __restrict__ src,
                                              short* __restrict__ dst, int n) {
  int i = (blockIdx.x * 256 + threadIdx.x) * 4;
  if (i + 3 < n) {
    float4 v = *(const float4*)(src + i);
    short4 o;
    o.x = f2bf(v.x);
    o.y = f2bf(v.y);
    o.z = f2bf(v.z);
    o.w = f2bf(v.w);
    *(short4*)(dst + i) = o;
  }
}

// ---------------------------------------------------------------------------
// K0b: transpose+convert x,y [B,C,N] f32 -> xT,yT [B,N,C] bf16.
__global__ __launch_bounds__(256) void k_transpose(
    const float* __restrict__ x, const float* __restrict__ y,
    short* __restrict__ xT, short* __restrict__ yT) {
  int bz = blockIdx.z;
  int b = bz >> 1;
  const float* src = (bz & 1) ? y : x;
  short* dst = (bz & 1) ? yT : xT;
  src += (size_t)b * Cc * Nn;
  dst += (size_t)b * Nn * Cc;
  __shared__ short tile[64][72];
  int n0 = blockIdx.x * 64, c0 = blockIdx.y * 64;
  int t = threadIdx.x;
#pragma unroll
  for (int i = 0; i < 16; i++) {
    int idx = t + i * 256;
    int cc = idx >> 6, nn = idx & 63;
    tile[cc][nn] = f2bf(src[(size_t)(c0 + cc) * Nn + n0 + nn]);
  }
  __syncthreads();
#pragma unroll
  for (int i = 0; i < 16; i++) {
    int idx = t + i * 256;
    int nn = idx >> 6, cc = idx & 63;
    dst[(size_t)(n0 + nn) * Cc + c0 + cc] = tile[cc][nn];
  }
}

// ---------------------------------------------------------------------------
// K1: fused Q,K projection. Wq/Wk tiles staged in LDS (swizzled); per-wave x
// A-frags in registers. grid (N/64, O/64, B), block 256.
__global__ __launch_bounds__(256) void k_proj_qk(
    const short* __restrict__ xT, const short* __restrict__ Wq,
    const float* __restrict__ bq, const short* __restrict__ Wk,
    const float* __restrict__ bk, short* __restrict__ Qt,
    short* __restrict__ Kt) {
  int b = blockIdx.z, n0 = blockIdx.x * 64, o0 = blockIdx.y * 64;
  int wave = threadIdx.x >> 6, lane = threadIdx.x & 63;
  int quad = lane >> 4, l16 = lane & 15;
  int sw = l16 & 7;
  __shared__ short Wqs[64 * 256];  // 32 KB, [o][c] swizzled
  __shared__ short Wks[64 * 256];  // 32 KB

  stage_row512((const char*)(Wq + (size_t)o0 * Cc), (char*)Wqs, wave, lane);
  stage_row512((const char*)(Wk + (size_t)o0 * Cc), (char*)Wks, wave, lane);
  // A frags to registers (vmcnt drained by the barrier below)
  const short* aptr =
      xT + (size_t)b * Nn * Cc + (size_t)(n0 + wave * 16 + l16) * Cc + quad * 8;
  bf16x8 areg[8];
#pragma unroll
  for (int ks = 0; ks < 8; ks++) areg[ks] = *(const bf16x8*)(aptr + ks * 32);

  f32x4 accQ[4], accK[4];
#pragma unroll
  for (int j = 0; j < 4; j++) {
    accQ[j] = f32x4{0.f, 0.f, 0.f, 0.f};
    accK[j] = f32x4{0.f, 0.f, 0.f, 0.f};
  }
  __syncthreads();
#pragma unroll
  for (int ks = 0; ks < 8; ks++) {
#pragma unroll
    for (int cj = 0; cj < 4; cj++) {
      int off = (cj * 16 + l16) * 512 + (((ks * 4 + quad) ^ sw) << 4);
      bf16x8 wqf = *(const bf16x8*)((const char*)Wqs + off);
      bf16x8 wkf = *(const bf16x8*)((const char*)Wks + off);
      accQ[cj] = mfma16(areg[ks], wqf, accQ[cj]);
      accK[cj] = mfma16(areg[ks], wkf, accK[cj]);
    }
  }
  // C-frag: row n = n0+wave*16+quad*4+r, col o = o0+cj*16+l16
#pragma unroll
  for (int cj = 0; cj < 4; cj++) {
    int o = o0 + cj * 16 + l16;
    int h = o >> 8, d = o & 255;
    float vbq = bq[o];
    float vbk = bk[o];
#pragma unroll
    for (int r = 0; r < 4; r++) {
      int n = n0 + wave * 16 + quad * 4 + r;
      size_t idx = (((size_t)(b * Hh + h) * Nn) + n) * 256 + d;
      Qt[idx] = f2bf(accQ[cj][r] + vbq);
      Kt[idx] = f2bf(accK[cj][r] + vbk);
    }
  }
}

// ---------------------------------------------------------------------------
// K2: V / yp projection. yT tile staged in LDS (swizzled); per-wave W A-frags
// in registers. grid (N/64, Ot/64, B), block 256.
template <bool FP32OUT>
__global__ __launch_bounds__(256) void k_proj_on(
    const short* __restrict__ yTs, const short* __restrict__ W,
    const float* __restrict__ bias, void* __restrict__ outp, int Ot) {
  int b = blockIdx.z, n0 = blockIdx.x * 64, o0 = blockIdx.y * 64;
  int wave = threadIdx.x >> 6, lane = threadIdx.x & 63;
  int quad = lane >> 4, l16 = lane & 15;
  int sw = l16 & 7;
  __shared__ short Ys[64 * 256];  // 32 KB, [n][c] swizzled

  stage_row512((const char*)(yTs + (size_t)b * Nn * Cc + (size_t)n0 * Cc),
               (char*)Ys, wave, lane);
  const short* aptr = W + (size_t)(o0 + wave * 16 + l16) * Cc + quad * 8;
  bf16x8 areg[8];
#pragma unroll
  for (int ks = 0; ks < 8; ks++) areg[ks] = *(const bf16x8*)(aptr + ks * 32);

  f32x4 acc[4];
#pragma unroll
  for (int j = 0; j < 4; j++) acc[j] = f32x4{0.f, 0.f, 0.f, 0.f};
  __syncthreads();
#pragma unroll
  for (int ks = 0; ks < 8; ks++) {
#pragma unroll
    for (int cj = 0; cj < 4; cj++) {
      bf16x8 bb = *(const bf16x8*)((const char*)Ys + (cj * 16 + l16) * 512 +
                                   (((ks * 4 + quad) ^ sw) << 4));
      acc[cj] = mfma16(areg[ks], bb, acc[cj]);
    }
  }
#pragma unroll
  for (int cj = 0; cj < 4; cj++) {
    int n = n0 + cj * 16 + l16;
#pragma unroll
    for (int r = 0; r < 4; r++) {
      int o = o0 + wave * 16 + quad * 4 + r;
      float v = acc[cj][r] + (bias ? bias[o] : 0.f);
      size_t idx = ((size_t)b * Ot + o) * Nn + n;
      if (FP32OUT)
        ((float*)outp)[idx] = v;
      else
        ((short*)outp)[idx] = f2bf(v);
    }
  }
}

// ---------------------------------------------------------------------------
// K3: flash attention, K/V staged in LDS (swizzled), XCD-aware block map so
// all 16 q-tiles of one (b,h) share an XCD's L2 (K/V slab fetched once/XCD).
// grid: 512 1-D, block 256 (wave w owns query rows w*16..+15).
__global__ __launch_bounds__(256) void k_attn(
    const short* __restrict__ Qt, const short* __restrict__ Kt,
    const short* __restrict__ Vv, const float* __restrict__ yp,
    const float* __restrict__ gamma, float* __restrict__ out) {
  int id = blockIdx.x;
  int bh = (id & 7) * 4 + (id >> 7);      // xcd*4 + group
  int q0 = ((id >> 3) & 15) * 64;
  int b = bh >> 3, h = bh & 7;
  int wave = threadIdx.x >> 6, lane = threadIdx.x & 63;
  int quad = lane >> 4, l16 = lane & 15;
  int sw = l16 & 7;
  const short* Qb = Qt + (size_t)bh * Nn * 256;
  const char* Kg = (const char*)(Kt + (size_t)bh * Nn * 256);  // key rows 512B
  const char* Vg = (const char*)(Vv + (size_t)bh * 256 * Nn);  // dv rows 2048B

  __shared__ short Klds[64 * 256];    // 32 KB [key][d] swizzled
  __shared__ short Vlds[256 * 64];    // 32 KB [dv][n-in-tile] swizzled
  __shared__ short plds[4][16][72];   // 9 KB per-wave P tile [q][key], padded

  // Q rows for this wave, in registers: A[m=l16][k=ks*32+quad*8+j]
  bf16x8 qreg[8];
  {
    const short* qp = Qb + (size_t)(q0 + wave * 16 + l16) * 256 + quad * 8;
#pragma unroll
    for (int ks = 0; ks < 8; ks++) qreg[ks] = *(const bf16x8*)(qp + ks * 32);
  }
  f32x4 oacc[16];
#pragma unroll
  for (int j = 0; j < 16; j++) oacc[j] = f32x4{0.f, 0.f, 0.f, 0.f};
  float m_i[4], l_i[4];
#pragma unroll
  for (int r = 0; r < 4; r++) {
    m_i[r] = -1e30f;
    l_i[r] = 0.f;
  }

  // prologue: stage tile 0
  stage_row512(Kg, (char*)Klds, wave, lane);
  stage_v(Vg, (char*)Vlds, 0, wave, lane);

  for (int kt = 0; kt < 16; kt++) {
    int k0 = kt * 64;
    __syncthreads();  // staged tiles ready (drains vmcnt) + wave sync
    // ---- S = Q K^T: [16 q][64 keys] per wave
    f32x4 sc[4];
#pragma unroll
    for (int j = 0; j < 4; j++) sc[j] = f32x4{0.f, 0.f, 0.f, 0.f};
#pragma unroll
    for (int ks = 0; ks < 8; ks++) {
#pragma unroll
      for (int cj = 0; cj < 4; cj++) {
        bf16x8 kb = *(const bf16x8*)((const char*)Klds +
                                     (cj * 16 + l16) * 512 +
                                     (((ks * 4 + quad) ^ sw) << 4));
        sc[cj] = mfma16(qreg[ks], kb, sc[cj]);
      }
    }
    // ---- online softmax: rows = quad*4+r, cols = cj*16+l16
    float alpha[4];
#pragma unroll
    for (int r = 0; r < 4; r++) {
      float v = fmaxf(fmaxf(sc[0][r], sc[1][r]), fmaxf(sc[2][r], sc[3][r]));
      v = fmaxf(v, __shfl_xor(v, 1));
      v = fmaxf(v, __shfl_xor(v, 2));
      v = fmaxf(v, __shfl_xor(v, 4));
      v = fmaxf(v, __shfl_xor(v, 8));
      float mn = fmaxf(m_i[r], v);
      alpha[r] = __expf(m_i[r] - mn);
      m_i[r] = mn;
    }
    float rs[4] = {0.f, 0.f, 0.f, 0.f};
#pragma unroll
    for (int cj = 0; cj < 4; cj++) {
#pragma unroll
      for (int r = 0; r < 4; r++) {
        float p = __expf(sc[cj][r] - m_i[r]);
        rs[r] += p;
        plds[wave][quad * 4 + r][cj * 16 + l16] = f2bf(p);
      }
    }
#pragma unroll
    for (int r = 0; r < 4; r++) {
      float v = rs[r];
      v += __shfl_xor(v, 1);
      v += __shfl_xor(v, 2);
      v += __shfl_xor(v, 4);
      v += __shfl_xor(v, 8);
      l_i[r] = l_i[r] * alpha[r] + v;
    }
#pragma unroll
    for (int j = 0; j < 16; j++)
#pragma unroll
      for (int r = 0; r < 4; r++) oacc[j][r] *= alpha[r];
    __syncthreads();  // plds ready; all waves done reading Klds
    // stage K(kt+1) — overlaps PV compute below
    if (kt < 15) stage_row512(Kg + (size_t)(k0 + 64) * 512, (char*)Klds, wave, lane);
    // ---- PV: O += P * V-frags
    // B-frag: col dv = dj*16+l16, k = keys. v0 = logical chunks quad (keys
    // quad*8..+7); v1 = logical chunk quad+4 (keys 32+quad*8..+7)  [fixed:
    // was quad+2 = +32B, must be +4 chunks = +64B to match ap1's keys 32..63]
    bf16x8 ap0 = *(const bf16x8*)&plds[wave][l16][quad * 8];
    bf16x8 ap1 = *(const bf16x8*)&plds[wave][l16][32 + quad * 8];
#pragma unroll
    for (int dj = 0; dj < 16; dj++) {
      const char* vrow = (const char*)Vlds + (dj * 16 + l16) * 128;
      bf16x8 v0 = *(const bf16x8*)(vrow + ((quad ^ sw) << 4));
      bf16x8 v1 = *(const bf16x8*)(vrow + (((quad + 4) ^ sw) << 4));
      oacc[dj] = mfma16(ap0, v0, oacc[dj]);
      oacc[dj] = mfma16(ap1, v1, oacc[dj]);
    }
    __syncthreads();  // all waves done reading Vlds (and plds)
    if (kt < 15) stage_v(Vg, (char*)Vlds, k0 + 64, wave, lane);
  }
  // epilogue: O rows q=quad*4+r contiguous -> float4 stores; fuse gamma/yp
  float gf = gamma[h];
  float sg = gf / (1.f + gf), sy = 1.f / (1.f + gf);
  int qq = q0 + wave * 16 + quad * 4;
#pragma unroll
  for (int dj = 0; dj < 16; dj++) {
    int dv = dj * 16 + l16;
    const float* ypp = yp + ((size_t)b * 256 + dv) * Nn + qq;
    float* op = out + ((size_t)b * Oo + h * 256 + dv) * Nn + qq;
    float4 yv = *(const float4*)ypp;
    float4 ov;
    ov.x = sg * (oacc[dj][0] / l_i[0]) + sy * yv.x;
    ov.y = sg * (oacc[dj][1] / l_i[1]) + sy * yv.y;
    ov.z = sg * (oacc[dj][2] / l_i[2]) + sy * yv.z;
    ov.w = sg * (oacc[dj][3] / l_i[3]) + sy * yv.w;
    *(float4*)op = ov;
  }
}

// ---------------------------------------------------------------------------
extern "C" void kernel_launch(void* const* d_in, const int* in_sizes, int n_in,
                              void* d_out, int out_size, void* d_ws,
                              size_t ws_size, hipStream_t stream) {
  const float* x = (const float*)d_in[0];
  const float* y = (const float*)d_in[1];
  const float* Wq = (const float*)d_in[2];
  const float* bq = (const float*)d_in[3];
  const float* Wk = (const float*)d_in[4];
  const float* bk = (const float*)d_in[5];
  const float* Wv = (const float*)d_in[6];
  const float* bv = (const float*)d_in[7];
  const float* Wp = (const float*)d_in[8];
  const float* gamma = (const float*)d_in[9];
  float* out = (float*)d_out;

  char* w = (char*)d_ws;
  short* Qt = (short*)(w + 0);          // 16 MB  [B,H,N,256] bf16
  short* Kt = (short*)(w + 16777216);   // 16 MB  [B,H,N,256] bf16
  short* Vv = (short*)(w + 33554432);   // 16 MB  [B,H*256,N] bf16
  short* xT = (short*)(w + 50331648);   // 2 MB   [B,N,C] bf16
  short* yT = (short*)(w + 52428800);   // 2 MB   [B,N,C] bf16
  float* yp = (float*)(w + 54525952);   // 4 MB   [B,256,N] f32
  short* Wqb = (short*)(w + 58720256);  // 1 MB   [2048,256] bf16
  short* Wkb = (short*)(w + 59768832);  // 1 MB
  short* Wvb = (short*)(w + 60817408);  // 1 MB
  short* Wpb = (short*)(w + 61865984);  // 128 KB [256,256] bf16

  k_pack<<<dim3(512), dim3(256), 0, stream>>>(Wq, Wqb, Oo * Cc);
  k_pack<<<dim3(512), dim3(256), 0, stream>>>(Wk, Wkb, Oo * Cc);
  k_pack<<<dim3(512), dim3(256), 0, stream>>>(Wv, Wvb, Oo * Cc);
  k_pack<<<dim3(64), dim3(256), 0, stream>>>(Wp, Wpb, Cc * Cc);
  k_transpose<<<dim3(Nn / 64, Cc / 64, 2 * Bb), dim3(256), 0, stream>>>(
      x, y, xT, yT);
  k_proj_qk<<<dim3(Nn / 64, Oo / 64, Bb), dim3(256), 0, stream>>>(
      xT, Wqb, bq, Wkb, bk, Qt, Kt);
  k_proj_on<false><<<dim3(Nn / 64, Oo / 64, Bb), dim3(256), 0, stream>>>(
      yT, Wvb, bv, (void*)Vv, Oo);
  k_proj_on<true><<<dim3(Nn / 64, Cc / 64, Bb), dim3(256), 0, stream>>>(
      yT, Wpb, nullptr, (void*)yp, Cc);
  k_attn<<<dim3(512), dim3(256), 0, stream>>>(Qt, Kt, Vv, yp, gamma, out);
}